// Round 1
// baseline (317.885 us; speedup 1.0000x reference)
//
#include <hip/hip_runtime.h>

#define BATCH 4
#define SQL 2048
#define SKL 2048
#define DIM 512
#define NR 257
#define NRP 272
#define RAD 128

typedef __bf16 bf16x8 __attribute__((ext_vector_type(8)));
typedef float f32x4 __attribute__((ext_vector_type(4)));
typedef unsigned short u16;
typedef u16 u16x4 __attribute__((ext_vector_type(4)));

__device__ inline u16 f2bf(float x) {
  union { float f; unsigned u; } v; v.f = x;
  unsigned r = v.u + 0x7FFF + ((v.u >> 16) & 1);   // RNE
  return (u16)(r >> 16);
}

// ---------------- conversion kernels ----------------

__global__ void cvt_kernel(const f32x4* __restrict__ src, u16x4* __restrict__ dst, int n4) {
  int i = blockIdx.x * 256 + threadIdx.x;
  if (i >= n4) return;
  f32x4 f = src[i];
  u16x4 o;
#pragma unroll
  for (int e = 0; e < 4; e++) o[e] = f2bf(f[e]);
  dst[i] = o;
}

__global__ void cvt_rel_kernel(const float* __restrict__ rel, u16* __restrict__ relb) {
  int i = blockIdx.x * 256 + threadIdx.x;  // < NRP*DIM
  int r = i >> 9;                          // / 512
  relb[i] = (r < NR) ? f2bf(rel[i]) : (u16)0;
}

// V [b][k][d] fp32 -> Vt [b][d][k] bf16
__global__ void transpose_v_kernel(const float* __restrict__ V, u16* __restrict__ Vt) {
  __shared__ float tile[32][33];
  int b = blockIdx.z;
  int k0 = blockIdx.x * 32, d0 = blockIdx.y * 32;
  int tx = threadIdx.x, ty = threadIdx.y;  // 32 x 8
#pragma unroll
  for (int r = 0; r < 4; r++)
    tile[ty + r * 8][tx] = V[((long)b * SKL + k0 + ty + r * 8) * DIM + d0 + tx];
  __syncthreads();
#pragma unroll
  for (int r = 0; r < 4; r++)
    Vt[((long)b * DIM + d0 + ty + r * 8) * SKL + k0 + tx] = f2bf(tile[tx][ty + r * 8]);
}

// ---------------- Qrel = Q @ rel^T : [8192][NRP] ----------------
// one wave per 16 rows; 17 column tiles of 16; K=512
__global__ __launch_bounds__(64) void qrel_kernel(const u16* __restrict__ Qb,
                                                  const u16* __restrict__ relb,
                                                  float* __restrict__ Qrel) {
  int m0 = blockIdx.x * 16;
  int lane = threadIdx.x;
  int fr = lane & 15, fk = (lane >> 4) * 8;
  f32x4 acc[17] = {};
  const u16* qrow = Qb + (long)(m0 + fr) * DIM + fk;
  const u16* rrow = relb + (long)fr * DIM + fk;
  for (int k0 = 0; k0 < DIM; k0 += 32) {
    bf16x8 a = *(const bf16x8*)(qrow + k0);
#pragma unroll
    for (int j = 0; j < 17; j++) {
      bf16x8 bb = *(const bf16x8*)(rrow + j * 16 * DIM + k0);
      acc[j] = __builtin_amdgcn_mfma_f32_16x16x32_bf16(a, bb, acc[j], 0, 0, 0);
    }
  }
  int cr = (lane >> 4) * 4, cc = lane & 15;
#pragma unroll
  for (int j = 0; j < 17; j++)
#pragma unroll
    for (int r = 0; r < 4; r++)
      Qrel[(long)(m0 + cr + r) * NRP + j * 16 + cc] = acc[j][r];
}

// ---------------- energy: E = (Q K^T + rel_gather) / sqrt(d) ----------------
// 128x128 tile, 256 threads (4 waves, each 64x64 = 4x4 of 16x16), BK=32
__global__ __launch_bounds__(256) void energy_kernel(const u16* __restrict__ Qb,
                                                     const u16* __restrict__ Kb,
                                                     const float* __restrict__ Qrel,
                                                     float* __restrict__ E) {
  int b = blockIdx.z;
  int m0 = blockIdx.y * 128;
  int n0 = blockIdx.x * 128;
  const u16* A = Qb + (long)b * SQL * DIM;
  const u16* Bp = Kb + (long)b * SKL * DIM;
  __shared__ u16 As[128 * 32];
  __shared__ u16 Bs[128 * 32];
  int tid = threadIdx.x;
  int wave = tid >> 6, lane = tid & 63;
  int wm = (wave >> 1) * 64, wn = (wave & 1) * 64;
  int ldr = tid >> 2, ldc = (tid & 3) * 8;
  int fr = lane & 15, fk = (lane >> 4) * 8;
  f32x4 acc[4][4] = {};
  for (int k0 = 0; k0 < DIM; k0 += 32) {
    bf16x8 av0 = *(const bf16x8*)(A + (long)(m0 + ldr) * DIM + k0 + ldc);
    bf16x8 av1 = *(const bf16x8*)(A + (long)(m0 + ldr + 64) * DIM + k0 + ldc);
    bf16x8 bv0 = *(const bf16x8*)(Bp + (long)(n0 + ldr) * DIM + k0 + ldc);
    bf16x8 bv1 = *(const bf16x8*)(Bp + (long)(n0 + ldr + 64) * DIM + k0 + ldc);
    __syncthreads();
    *(bf16x8*)(As + ldr * 32 + ldc) = av0;
    *(bf16x8*)(As + (ldr + 64) * 32 + ldc) = av1;
    *(bf16x8*)(Bs + ldr * 32 + ldc) = bv0;
    *(bf16x8*)(Bs + (ldr + 64) * 32 + ldc) = bv1;
    __syncthreads();
    bf16x8 af[4], bfr[4];
#pragma unroll
    for (int i = 0; i < 4; i++) af[i] = *(const bf16x8*)(As + (wm + i * 16 + fr) * 32 + fk);
#pragma unroll
    for (int j = 0; j < 4; j++) bfr[j] = *(const bf16x8*)(Bs + (wn + j * 16 + fr) * 32 + fk);
#pragma unroll
    for (int i = 0; i < 4; i++)
#pragma unroll
      for (int j = 0; j < 4; j++)
        acc[i][j] = __builtin_amdgcn_mfma_f32_16x16x32_bf16(af[i], bfr[j], acc[i][j], 0, 0, 0);
  }
  const float inv_norm = 0.04419417382415922f;  // 1/sqrt(512)
  int cr = (lane >> 4) * 4, cc = lane & 15;
#pragma unroll
  for (int i = 0; i < 4; i++) {
#pragma unroll
    for (int r = 0; r < 4; r++) {
      int q = m0 + wm + i * 16 + cr + r;
      const float* qrow = Qrel + ((long)b * SQL + q) * NRP;
      float* erow = E + ((long)b * SQL + q) * SKL;
#pragma unroll
      for (int j = 0; j < 4; j++) {
        int k = n0 + wn + j * 16 + cc;
        int dlt = k - q;
        dlt = dlt < -RAD ? -RAD : (dlt > RAD ? RAD : dlt);
        erow[k] = (acc[i][j][r] + qrow[dlt + RAD]) * inv_norm;
      }
    }
  }
}

// ---------------- softmax (in-place, one block per row of 2048) ----------------
__global__ __launch_bounds__(256) void softmax_kernel(float* __restrict__ E) {
  long row = blockIdx.x;
  f32x4* p4 = (f32x4*)(E + row * SKL);
  int tid = threadIdx.x;
  int wave = tid >> 6, lane = tid & 63;
  f32x4 v0 = p4[tid], v1 = p4[tid + 256];
  float m = -1e30f;
#pragma unroll
  for (int i = 0; i < 4; i++) { m = fmaxf(m, v0[i]); m = fmaxf(m, v1[i]); }
  for (int o = 32; o > 0; o >>= 1) m = fmaxf(m, __shfl_xor(m, o));
  __shared__ float red[4];
  if (lane == 0) red[wave] = m;
  __syncthreads();
  m = fmaxf(fmaxf(red[0], red[1]), fmaxf(red[2], red[3]));
  __syncthreads();
  float s = 0.0f;
  f32x4 e0, e1;
#pragma unroll
  for (int i = 0; i < 4; i++) { e0[i] = __expf(v0[i] - m); s += e0[i]; }
#pragma unroll
  for (int i = 0; i < 4; i++) { e1[i] = __expf(v1[i] - m); s += e1[i]; }
  for (int o = 32; o > 0; o >>= 1) s += __shfl_xor(s, o);
  if (lane == 0) red[wave] = s;
  __syncthreads();
  s = red[0] + red[1] + red[2] + red[3];
  float inv = 1.0f / s;
  p4[tid] = e0 * inv;
  p4[tid + 256] = e1 * inv;
}

// ---------------- Z = attn @ V (attn fp32 -> bf16 in staging; Vt is [b][d][k]) ----------------
__global__ __launch_bounds__(256) void z_kernel(const float* __restrict__ attn,
                                                const u16* __restrict__ Vt,
                                                float* __restrict__ Z) {
  int b = blockIdx.z;
  int m0 = blockIdx.y * 128;
  int n0 = blockIdx.x * 128;
  const float* A = attn + (long)b * SQL * SKL;
  const u16* Bp = Vt + (long)b * DIM * SKL;
  __shared__ u16 As[128 * 32];
  __shared__ u16 Bs[128 * 32];
  int tid = threadIdx.x;
  int wave = tid >> 6, lane = tid & 63;
  int wm = (wave >> 1) * 64, wn = (wave & 1) * 64;
  int ar = tid >> 3, ac = (tid & 7) * 4;
  int br = tid >> 2, bc = (tid & 3) * 8;
  int fr = lane & 15, fk = (lane >> 4) * 8;
  f32x4 acc[4][4] = {};
  for (int k0 = 0; k0 < SKL; k0 += 32) {
    f32x4 av[4];
#pragma unroll
    for (int p = 0; p < 4; p++)
      av[p] = *(const f32x4*)(A + (long)(m0 + ar + p * 32) * SKL + k0 + ac);
    bf16x8 bv0 = *(const bf16x8*)(Bp + (long)(n0 + br) * SKL + k0 + bc);
    bf16x8 bv1 = *(const bf16x8*)(Bp + (long)(n0 + br + 64) * SKL + k0 + bc);
    __syncthreads();
#pragma unroll
    for (int p = 0; p < 4; p++) {
      u16x4 o;
#pragma unroll
      for (int e = 0; e < 4; e++) o[e] = f2bf(av[p][e]);
      *(u16x4*)(As + (ar + p * 32) * 32 + ac) = o;
    }
    *(bf16x8*)(Bs + br * 32 + bc) = bv0;
    *(bf16x8*)(Bs + (br + 64) * 32 + bc) = bv1;
    __syncthreads();
    bf16x8 af[4], bfr[4];
#pragma unroll
    for (int i = 0; i < 4; i++) af[i] = *(const bf16x8*)(As + (wm + i * 16 + fr) * 32 + fk);
#pragma unroll
    for (int j = 0; j < 4; j++) bfr[j] = *(const bf16x8*)(Bs + (wn + j * 16 + fr) * 32 + fk);
#pragma unroll
    for (int i = 0; i < 4; i++)
#pragma unroll
      for (int j = 0; j < 4; j++)
        acc[i][j] = __builtin_amdgcn_mfma_f32_16x16x32_bf16(af[i], bfr[j], acc[i][j], 0, 0, 0);
  }
  int cr = (lane >> 4) * 4, cc = lane & 15;
#pragma unroll
  for (int i = 0; i < 4; i++)
#pragma unroll
    for (int r = 0; r < 4; r++) {
      int q = m0 + wm + i * 16 + cr + r;
      float* zrow = Z + ((long)b * SQL + q) * DIM;
#pragma unroll
      for (int j = 0; j < 4; j++)
        zrow[n0 + wn + j * 16 + cc] = acc[i][j][r];
    }
}

// ---------------- launch ----------------

extern "C" void kernel_launch(void* const* d_in, const int* in_sizes, int n_in,
                              void* d_out, int out_size, void* d_ws, size_t ws_size,
                              hipStream_t stream) {
  const float* Q = (const float*)d_in[0];
  const float* K = (const float*)d_in[1];
  const float* V = (const float*)d_in[2];
  const float* rel = (const float*)d_in[3];
  float* attn = (float*)d_out;                       // [4][2048][2048]
  float* Z = attn + (long)BATCH * SQL * SKL;         // [4][2048][512]

  char* ws = (char*)d_ws;
  u16* Qb   = (u16*)ws;                    //  8 MiB  bf16 Q [b][q][d]
  u16* Kb   = (u16*)(ws + 8388608);        //  8 MiB  bf16 K [b][k][d]
  u16* Vt   = (u16*)(ws + 16777216);       //  8 MiB  bf16 V^T [b][d][k]
  u16* relb = (u16*)(ws + 25165824);       //  272 KiB bf16 rel padded [272][512]
  float* Qrel = (float*)(ws + 25444352);   //  8.5 MiB fp32 Qrel [8192][272]

  cvt_kernel<<<4096, 256, 0, stream>>>((const f32x4*)Q, (u16x4*)Qb, 1048576);
  cvt_kernel<<<4096, 256, 0, stream>>>((const f32x4*)K, (u16x4*)Kb, 1048576);
  cvt_rel_kernel<<<544, 256, 0, stream>>>(rel, relb);
  transpose_v_kernel<<<dim3(64, 16, BATCH), dim3(32, 8), 0, stream>>>(V, Vt);
  qrel_kernel<<<512, 64, 0, stream>>>(Qb, relb, Qrel);
  energy_kernel<<<dim3(16, 16, BATCH), 256, 0, stream>>>(Qb, Kb, Qrel, attn);
  softmax_kernel<<<8192, 256, 0, stream>>>(attn);
  z_kernel<<<dim3(4, 16, BATCH), 256, 0, stream>>>(attn, Vt, Z);
}

// Round 2
// 277.830 us; speedup vs baseline: 1.1442x; 1.1442x over previous
//
#include <hip/hip_runtime.h>

#define BATCH 4
#define SQL 2048
#define SKL 2048
#define DIM 512
#define NR 257
#define NRP 272
#define RAD 128

typedef __bf16 bf16x8 __attribute__((ext_vector_type(8)));
typedef float f32x4 __attribute__((ext_vector_type(4)));
typedef unsigned short u16;
typedef u16 u16x4 __attribute__((ext_vector_type(4)));
typedef u16 u16x8 __attribute__((ext_vector_type(8)));

__device__ inline u16 f2bf(float x) {
  union { float f; unsigned u; } v; v.f = x;
  unsigned r = v.u + 0x7FFF + ((v.u >> 16) & 1);   // RNE
  return (u16)(r >> 16);
}

__device__ inline void glds16(const u16* g, const u16* l) {
  __builtin_amdgcn_global_load_lds(
      (const __attribute__((address_space(1))) void*)g,
      (__attribute__((address_space(3))) void*)l, 16, 0, 0);
}

// ---------------- conversion kernels ----------------

__global__ void cvt_kernel(const f32x4* __restrict__ src, u16x4* __restrict__ dst, int n4) {
  int i = blockIdx.x * 256 + threadIdx.x;
  if (i >= n4) return;
  f32x4 f = src[i];
  u16x4 o;
#pragma unroll
  for (int e = 0; e < 4; e++) o[e] = f2bf(f[e]);
  dst[i] = o;
}

__global__ void cvt_rel_kernel(const float* __restrict__ rel, u16* __restrict__ relb) {
  int i = blockIdx.x * 256 + threadIdx.x;  // < NRP*DIM
  int r = i >> 9;                          // / 512
  relb[i] = (r < NR) ? f2bf(rel[i]) : (u16)0;
}

// V [b][k][d] fp32 -> Vt [b][d][k] bf16
__global__ void transpose_v_kernel(const float* __restrict__ V, u16* __restrict__ Vt) {
  __shared__ float tile[32][33];
  int b = blockIdx.z;
  int k0 = blockIdx.x * 32, d0 = blockIdx.y * 32;
  int tx = threadIdx.x, ty = threadIdx.y;  // 32 x 8
#pragma unroll
  for (int r = 0; r < 4; r++)
    tile[ty + r * 8][tx] = V[((long)b * SKL + k0 + ty + r * 8) * DIM + d0 + tx];
  __syncthreads();
#pragma unroll
  for (int r = 0; r < 4; r++)
    Vt[((long)b * DIM + d0 + ty + r * 8) * SKL + k0 + tx] = f2bf(tile[tx][ty + r * 8]);
}

// ---------------- Qrel = Q @ rel^T : [8192][NRP] ----------------
__global__ __launch_bounds__(64) void qrel_kernel(const u16* __restrict__ Qb,
                                                  const u16* __restrict__ relb,
                                                  float* __restrict__ Qrel) {
  int m0 = blockIdx.x * 16;
  int lane = threadIdx.x;
  int fr = lane & 15, fk = (lane >> 4) * 8;
  f32x4 acc[17] = {};
  const u16* qrow = Qb + (long)(m0 + fr) * DIM + fk;
  const u16* rrow = relb + (long)fr * DIM + fk;
  for (int k0 = 0; k0 < DIM; k0 += 32) {
    bf16x8 a = *(const bf16x8*)(qrow + k0);
#pragma unroll
    for (int j = 0; j < 17; j++) {
      bf16x8 bb = *(const bf16x8*)(rrow + j * 16 * DIM + k0);
      acc[j] = __builtin_amdgcn_mfma_f32_16x16x32_bf16(a, bb, acc[j], 0, 0, 0);
    }
  }
  int cr = (lane >> 4) * 4, cc = lane & 15;
#pragma unroll
  for (int j = 0; j < 17; j++)
#pragma unroll
    for (int r = 0; r < 4; r++)
      Qrel[(long)(m0 + cr + r) * NRP + j * 16 + cc] = acc[j][r];
}

// ---------------- energy: S = bf16((Q K^T + rel_gather) / sqrt(d)) ----------------
// 128x128 tile, 4 waves (2x2 of 64x64), BK=32, global_load_lds staging
__global__ __launch_bounds__(256) void energy_kernel(const u16* __restrict__ Qb,
                                                     const u16* __restrict__ Kb,
                                                     const float* __restrict__ Qrel,
                                                     u16* __restrict__ S) {
  int b = blockIdx.z;
  int m0 = blockIdx.y * 128;
  int n0 = blockIdx.x * 128;
  const u16* A = Qb + (long)b * SQL * DIM;
  const u16* Bp = Kb + (long)b * SKL * DIM;
  __shared__ u16 As[128 * 32];
  __shared__ u16 Bs[128 * 32];
  int tid = threadIdx.x;
  int wave = tid >> 6, lane = tid & 63;
  int wm = (wave >> 1) * 64, wn = (wave & 1) * 64;
  int fr = lane & 15, fk = (lane >> 4) * 8;
  int srow = wave * 32 + (lane >> 2);   // staging row for issue t=0 (t=1: +16)
  int scol = (lane & 3) * 8;
  f32x4 acc[4][4] = {};
  for (int k0 = 0; k0 < DIM; k0 += 32) {
    __syncthreads();
    glds16(A + (long)(m0 + srow) * DIM + k0 + scol, As + (wave * 2 + 0) * 512);
    glds16(A + (long)(m0 + srow + 16) * DIM + k0 + scol, As + (wave * 2 + 1) * 512);
    glds16(Bp + (long)(n0 + srow) * DIM + k0 + scol, Bs + (wave * 2 + 0) * 512);
    glds16(Bp + (long)(n0 + srow + 16) * DIM + k0 + scol, Bs + (wave * 2 + 1) * 512);
    __syncthreads();
    bf16x8 af[4], bfr[4];
#pragma unroll
    for (int i = 0; i < 4; i++) af[i] = *(const bf16x8*)(As + (wm + i * 16 + fr) * 32 + fk);
#pragma unroll
    for (int j = 0; j < 4; j++) bfr[j] = *(const bf16x8*)(Bs + (wn + j * 16 + fr) * 32 + fk);
#pragma unroll
    for (int i = 0; i < 4; i++)
#pragma unroll
      for (int j = 0; j < 4; j++)
        acc[i][j] = __builtin_amdgcn_mfma_f32_16x16x32_bf16(af[i], bfr[j], acc[i][j], 0, 0, 0);
  }
  const float inv_norm = 0.04419417382415922f;  // 1/sqrt(512)
  int cr = (lane >> 4) * 4, cc = lane & 15;
#pragma unroll
  for (int i = 0; i < 4; i++) {
#pragma unroll
    for (int r = 0; r < 4; r++) {
      int q = m0 + wm + i * 16 + cr + r;
      const float* qrow = Qrel + ((long)b * SQL + q) * NRP;
      u16* sr = S + ((long)b * SQL + q) * SKL;
#pragma unroll
      for (int j = 0; j < 4; j++) {
        int k = n0 + wn + j * 16 + cc;
        int dlt = k - q;
        dlt = dlt < -RAD ? -RAD : (dlt > RAD ? RAD : dlt);
        sr[k] = f2bf((acc[i][j][r] + qrow[dlt + RAD]) * inv_norm);
      }
    }
  }
}

// ---------------- softmax: read bf16 logits S, write fp32 attn + bf16 probs (S in-place) ----
__global__ __launch_bounds__(256) void softmax_kernel(u16* __restrict__ S,
                                                      float* __restrict__ attn) {
  long row = blockIdx.x;
  u16* srow = S + row * SKL;
  float* arow = attn + row * SKL;
  int tid = threadIdx.x;
  int wave = tid >> 6, lane = tid & 63;
  bf16x8 v = *(const bf16x8*)(srow + tid * 8);
  float f[8];
#pragma unroll
  for (int e = 0; e < 8; e++) f[e] = (float)v[e];
  float m = -1e30f;
#pragma unroll
  for (int e = 0; e < 8; e++) m = fmaxf(m, f[e]);
  for (int o = 32; o > 0; o >>= 1) m = fmaxf(m, __shfl_xor(m, o));
  __shared__ float red[4];
  if (lane == 0) red[wave] = m;
  __syncthreads();
  m = fmaxf(fmaxf(red[0], red[1]), fmaxf(red[2], red[3]));
  __syncthreads();
  float s = 0.0f;
  float e8[8];
#pragma unroll
  for (int e = 0; e < 8; e++) { e8[e] = __expf(f[e] - m); s += e8[e]; }
  for (int o = 32; o > 0; o >>= 1) s += __shfl_xor(s, o);
  if (lane == 0) red[wave] = s;
  __syncthreads();
  s = red[0] + red[1] + red[2] + red[3];
  float inv = 1.0f / s;
  f32x4 o0, o1;
  u16x8 pb;
#pragma unroll
  for (int e = 0; e < 4; e++) {
    float p = e8[e] * inv;
    o0[e] = p; pb[e] = f2bf(p);
  }
#pragma unroll
  for (int e = 0; e < 4; e++) {
    float p = e8[e + 4] * inv;
    o1[e] = p; pb[e + 4] = f2bf(p);
  }
  *(f32x4*)(arow + tid * 8) = o0;
  *(f32x4*)(arow + tid * 8 + 4) = o1;
  *(u16x8*)(srow + tid * 8) = pb;
}

// ---------------- Z = P @ V  (P = bf16 probs in S; Vt is [b][d][k] bf16) ----------------
// 64x128 tile (M x N), 4 waves (2x2 of 32x64), BK=32, global_load_lds staging
__global__ __launch_bounds__(256) void z_kernel(const u16* __restrict__ S,
                                                const u16* __restrict__ Vt,
                                                float* __restrict__ Z) {
  int b = blockIdx.z;
  int m0 = blockIdx.y * 64;
  int n0 = blockIdx.x * 128;
  const u16* A = S + (long)b * SQL * SKL;
  const u16* Bp = Vt + (long)b * DIM * SKL;
  __shared__ u16 As[64 * 32];
  __shared__ u16 Bs[128 * 32];
  int tid = threadIdx.x;
  int wave = tid >> 6, lane = tid & 63;
  int wm = (wave >> 1) * 32, wn = (wave & 1) * 64;
  int fr = lane & 15, fk = (lane >> 4) * 8;
  int srowA = wave * 16 + (lane >> 2);
  int srowB = wave * 32 + (lane >> 2);
  int scol = (lane & 3) * 8;
  f32x4 acc[2][4] = {};
  for (int k0 = 0; k0 < SKL; k0 += 32) {
    __syncthreads();
    glds16(A + (long)(m0 + srowA) * SKL + k0 + scol, As + wave * 512);
    glds16(Bp + (long)(n0 + srowB) * SKL + k0 + scol, Bs + (wave * 2 + 0) * 512);
    glds16(Bp + (long)(n0 + srowB + 16) * SKL + k0 + scol, Bs + (wave * 2 + 1) * 512);
    __syncthreads();
    bf16x8 af[2], bfr[4];
#pragma unroll
    for (int i = 0; i < 2; i++) af[i] = *(const bf16x8*)(As + (wm + i * 16 + fr) * 32 + fk);
#pragma unroll
    for (int j = 0; j < 4; j++) bfr[j] = *(const bf16x8*)(Bs + (wn + j * 16 + fr) * 32 + fk);
#pragma unroll
    for (int i = 0; i < 2; i++)
#pragma unroll
      for (int j = 0; j < 4; j++)
        acc[i][j] = __builtin_amdgcn_mfma_f32_16x16x32_bf16(af[i], bfr[j], acc[i][j], 0, 0, 0);
  }
  int cr = (lane >> 4) * 4, cc = lane & 15;
#pragma unroll
  for (int i = 0; i < 2; i++)
#pragma unroll
    for (int r = 0; r < 4; r++) {
      int q = m0 + wm + i * 16 + cr + r;
      float* zrow = Z + ((long)b * SQL + q) * DIM;
#pragma unroll
      for (int j = 0; j < 4; j++)
        zrow[n0 + wn + j * 16 + cc] = acc[i][j][r];
    }
}

// ---------------- launch ----------------

extern "C" void kernel_launch(void* const* d_in, const int* in_sizes, int n_in,
                              void* d_out, int out_size, void* d_ws, size_t ws_size,
                              hipStream_t stream) {
  const float* Q = (const float*)d_in[0];
  const float* K = (const float*)d_in[1];
  const float* V = (const float*)d_in[2];
  const float* rel = (const float*)d_in[3];
  float* attn = (float*)d_out;                       // [4][2048][2048]
  float* Z = attn + (long)BATCH * SQL * SKL;         // [4][2048][512]

  char* ws = (char*)d_ws;
  u16* Qb   = (u16*)ws;                    //  8 MiB  bf16 Q [b][q][d]
  u16* Kb   = (u16*)(ws + 8388608);        //  8 MiB  bf16 K [b][k][d]
  u16* Vt   = (u16*)(ws + 16777216);       //  8 MiB  bf16 V^T [b][d][k]
  u16* relb = (u16*)(ws + 25165824);       //  272 KiB bf16 rel padded [272][512]
  float* Qrel = (float*)(ws + 25444352);   //  8.5 MiB fp32 Qrel [8192][272]
  u16* S    = (u16*)(ws + 34357248);       //  32 MiB  bf16 scores/probs [b][q][k]

  cvt_kernel<<<4096, 256, 0, stream>>>((const f32x4*)Q, (u16x4*)Qb, 1048576);
  cvt_kernel<<<4096, 256, 0, stream>>>((const f32x4*)K, (u16x4*)Kb, 1048576);
  cvt_rel_kernel<<<544, 256, 0, stream>>>(rel, relb);
  transpose_v_kernel<<<dim3(64, 16, BATCH), dim3(32, 8), 0, stream>>>(V, Vt);
  qrel_kernel<<<512, 64, 0, stream>>>(Qb, relb, Qrel);
  energy_kernel<<<dim3(16, 16, BATCH), 256, 0, stream>>>(Qb, Kb, Qrel, S);
  softmax_kernel<<<8192, 256, 0, stream>>>(S, attn);
  z_kernel<<<dim3(4, 32, BATCH), 256, 0, stream>>>(S, Vt, Z);
}

// Round 3
// 248.587 us; speedup vs baseline: 1.2788x; 1.1176x over previous
//
#include <hip/hip_runtime.h>

#define BATCH 4
#define SQL 2048
#define SKL 2048
#define DIM 512
#define NR 257
#define NRP 288
#define RAD 128

typedef __bf16 bf16x8 __attribute__((ext_vector_type(8)));
typedef float f32x4 __attribute__((ext_vector_type(4)));
typedef unsigned short u16;
typedef u16 u16x4 __attribute__((ext_vector_type(4)));
typedef u16 u16x8 __attribute__((ext_vector_type(8)));

__device__ inline u16 f2bf(float x) {
  union { float f; unsigned u; } v; v.f = x;
  unsigned r = v.u + 0x7FFF + ((v.u >> 16) & 1);   // RNE
  return (u16)(r >> 16);
}

__device__ inline void glds16(const u16* g, const u16* l) {
  __builtin_amdgcn_global_load_lds(
      (const __attribute__((address_space(1))) void*)g,
      (__attribute__((address_space(3))) void*)l, 16, 0, 0);
}

// ---------------- conversion kernels ----------------

__global__ void cvt_kernel(const f32x4* __restrict__ src, u16x4* __restrict__ dst, int n4) {
  int i = blockIdx.x * 256 + threadIdx.x;
  if (i >= n4) return;
  f32x4 f = src[i];
  u16x4 o;
#pragma unroll
  for (int e = 0; e < 4; e++) o[e] = f2bf(f[e]);
  dst[i] = o;
}

__global__ void cvt_rel_kernel(const float* __restrict__ rel, u16* __restrict__ relb) {
  int i = blockIdx.x * 256 + threadIdx.x;  // < NRP*DIM
  int r = i >> 9;                          // / 512
  relb[i] = (r < NR) ? f2bf(rel[i]) : (u16)0;
}

// V [b][k][d] fp32 -> Vt [b][d][k] bf16
__global__ void transpose_v_kernel(const float* __restrict__ V, u16* __restrict__ Vt) {
  __shared__ float tile[32][33];
  int b = blockIdx.z;
  int k0 = blockIdx.x * 32, d0 = blockIdx.y * 32;
  int tx = threadIdx.x, ty = threadIdx.y;  // 32 x 8
#pragma unroll
  for (int r = 0; r < 4; r++)
    tile[ty + r * 8][tx] = V[((long)b * SKL + k0 + ty + r * 8) * DIM + d0 + tx];
  __syncthreads();
#pragma unroll
  for (int r = 0; r < 4; r++)
    Vt[((long)b * DIM + d0 + ty + r * 8) * SKL + k0 + tx] = f2bf(tile[tx][ty + r * 8]);
}

// ---------------- Qrel = Q @ rel^T : [8192][NRP] ----------------
// grid (128, 9) x 256 threads; wave w: rows m0+w*16..+16, col tiles {2y, 2y+1}
__global__ __launch_bounds__(256) void qrel_kernel(const u16* __restrict__ Qb,
                                                   const u16* __restrict__ relb,
                                                   float* __restrict__ Qrel) {
  int tid = threadIdx.x;
  int wave = tid >> 6, lane = tid & 63;
  int m0 = blockIdx.x * 64 + wave * 16;
  int j0 = blockIdx.y * 2;                 // col tiles j0, j0+1
  int fr = lane & 15, fk = (lane >> 4) * 8;
  f32x4 acc[2] = {};
  const u16* qrow = Qb + (long)(m0 + fr) * DIM + fk;
  const u16* r0 = relb + (long)(j0 * 16 + fr) * DIM + fk;
  const u16* r1 = r0 + 16 * DIM;
  for (int k0 = 0; k0 < DIM; k0 += 32) {
    bf16x8 a = *(const bf16x8*)(qrow + k0);
    bf16x8 b0 = *(const bf16x8*)(r0 + k0);
    bf16x8 b1 = *(const bf16x8*)(r1 + k0);
    acc[0] = __builtin_amdgcn_mfma_f32_16x16x32_bf16(a, b0, acc[0], 0, 0, 0);
    acc[1] = __builtin_amdgcn_mfma_f32_16x16x32_bf16(a, b1, acc[1], 0, 0, 0);
  }
  int cr = (lane >> 4) * 4, cc = lane & 15;
#pragma unroll
  for (int t = 0; t < 2; t++)
#pragma unroll
    for (int r = 0; r < 4; r++)
      Qrel[(long)(m0 + cr + r) * NRP + (j0 + t) * 16 + cc] = acc[t][r];
}

// ---------------- energy: S = bf16((Q K^T + rel_gather) / sqrt(d)) ----------------
// 128x128 tile, 4 waves (2x2 of 64x64), BK=32, global_load_lds staging
__global__ __launch_bounds__(256) void energy_kernel(const u16* __restrict__ Qb,
                                                     const u16* __restrict__ Kb,
                                                     const float* __restrict__ Qrel,
                                                     u16* __restrict__ S) {
  int b = blockIdx.z;
  int m0 = blockIdx.y * 128;
  int n0 = blockIdx.x * 128;
  const u16* A = Qb + (long)b * SQL * DIM;
  const u16* Bp = Kb + (long)b * SKL * DIM;
  __shared__ u16 As[128 * 32];
  __shared__ u16 Bs[128 * 32];
  int tid = threadIdx.x;
  int wave = tid >> 6, lane = tid & 63;
  int wm = (wave >> 1) * 64, wn = (wave & 1) * 64;
  int fr = lane & 15, fk = (lane >> 4) * 8;
  int srow = wave * 32 + (lane >> 2);   // staging row for issue t=0 (t=1: +16)
  int scol = (lane & 3) * 8;
  f32x4 acc[4][4] = {};
  for (int k0 = 0; k0 < DIM; k0 += 32) {
    __syncthreads();
    glds16(A + (long)(m0 + srow) * DIM + k0 + scol, As + (wave * 2 + 0) * 512);
    glds16(A + (long)(m0 + srow + 16) * DIM + k0 + scol, As + (wave * 2 + 1) * 512);
    glds16(Bp + (long)(n0 + srow) * DIM + k0 + scol, Bs + (wave * 2 + 0) * 512);
    glds16(Bp + (long)(n0 + srow + 16) * DIM + k0 + scol, Bs + (wave * 2 + 1) * 512);
    __syncthreads();
    bf16x8 af[4], bfr[4];
#pragma unroll
    for (int i = 0; i < 4; i++) af[i] = *(const bf16x8*)(As + (wm + i * 16 + fr) * 32 + fk);
#pragma unroll
    for (int j = 0; j < 4; j++) bfr[j] = *(const bf16x8*)(Bs + (wn + j * 16 + fr) * 32 + fk);
#pragma unroll
    for (int i = 0; i < 4; i++)
#pragma unroll
      for (int j = 0; j < 4; j++)
        acc[i][j] = __builtin_amdgcn_mfma_f32_16x16x32_bf16(af[i], bfr[j], acc[i][j], 0, 0, 0);
  }
  const float inv_norm = 0.04419417382415922f;  // 1/sqrt(512)
  int cr = (lane >> 4) * 4, cc = lane & 15;
#pragma unroll
  for (int i = 0; i < 4; i++) {
#pragma unroll
    for (int r = 0; r < 4; r++) {
      int q = m0 + wm + i * 16 + cr + r;
      const float* qrow = Qrel + ((long)b * SQL + q) * NRP;
      u16* sr = S + ((long)b * SQL + q) * SKL;
#pragma unroll
      for (int j = 0; j < 4; j++) {
        int k = n0 + wn + j * 16 + cc;
        int dlt = k - q;
        dlt = dlt < -RAD ? -RAD : (dlt > RAD ? RAD : dlt);
        sr[k] = f2bf((acc[i][j][r] + qrow[dlt + RAD]) * inv_norm);
      }
    }
  }
}

// ---------------- softmax: read bf16 logits S, write fp32 attn + bf16 probs (S in-place) ----
__global__ __launch_bounds__(256) void softmax_kernel(u16* __restrict__ S,
                                                      float* __restrict__ attn) {
  long row = blockIdx.x;
  u16* srow = S + row * SKL;
  float* arow = attn + row * SKL;
  int tid = threadIdx.x;
  int wave = tid >> 6, lane = tid & 63;
  bf16x8 v = *(const bf16x8*)(srow + tid * 8);
  float f[8];
#pragma unroll
  for (int e = 0; e < 8; e++) f[e] = (float)v[e];
  float m = -1e30f;
#pragma unroll
  for (int e = 0; e < 8; e++) m = fmaxf(m, f[e]);
  for (int o = 32; o > 0; o >>= 1) m = fmaxf(m, __shfl_xor(m, o));
  __shared__ float red[4];
  if (lane == 0) red[wave] = m;
  __syncthreads();
  m = fmaxf(fmaxf(red[0], red[1]), fmaxf(red[2], red[3]));
  __syncthreads();
  float s = 0.0f;
  float e8[8];
#pragma unroll
  for (int e = 0; e < 8; e++) { e8[e] = __expf(f[e] - m); s += e8[e]; }
  for (int o = 32; o > 0; o >>= 1) s += __shfl_xor(s, o);
  if (lane == 0) red[wave] = s;
  __syncthreads();
  s = red[0] + red[1] + red[2] + red[3];
  float inv = 1.0f / s;
  f32x4 o0, o1;
  u16x8 pb;
#pragma unroll
  for (int e = 0; e < 4; e++) {
    float p = e8[e] * inv;
    o0[e] = p; pb[e] = f2bf(p);
  }
#pragma unroll
  for (int e = 0; e < 4; e++) {
    float p = e8[e + 4] * inv;
    o1[e] = p; pb[e + 4] = f2bf(p);
  }
  *(f32x4*)(arow + tid * 8) = o0;
  *(f32x4*)(arow + tid * 8 + 4) = o1;
  *(u16x8*)(srow + tid * 8) = pb;
}

// ---------------- Z = P @ V  (P = bf16 probs in S; Vt is [b][d][k] bf16) ----------------
// 64x128 tile (M x N), 4 waves (2x2 of 32x64), BK=32, global_load_lds staging
__global__ __launch_bounds__(256) void z_kernel(const u16* __restrict__ S,
                                                const u16* __restrict__ Vt,
                                                float* __restrict__ Z) {
  int b = blockIdx.z;
  int m0 = blockIdx.y * 64;
  int n0 = blockIdx.x * 128;
  const u16* A = S + (long)b * SQL * SKL;
  const u16* Bp = Vt + (long)b * DIM * SKL;
  __shared__ u16 As[64 * 32];
  __shared__ u16 Bs[128 * 32];
  int tid = threadIdx.x;
  int wave = tid >> 6, lane = tid & 63;
  int wm = (wave >> 1) * 32, wn = (wave & 1) * 64;
  int fr = lane & 15, fk = (lane >> 4) * 8;
  int srowA = wave * 16 + (lane >> 2);
  int srowB = wave * 32 + (lane >> 2);
  int scol = (lane & 3) * 8;
  f32x4 acc[2][4] = {};
  for (int k0 = 0; k0 < SKL; k0 += 32) {
    __syncthreads();
    glds16(A + (long)(m0 + srowA) * SKL + k0 + scol, As + wave * 512);
    glds16(Bp + (long)(n0 + srowB) * SKL + k0 + scol, Bs + (wave * 2 + 0) * 512);
    glds16(Bp + (long)(n0 + srowB + 16) * SKL + k0 + scol, Bs + (wave * 2 + 1) * 512);
    __syncthreads();
    bf16x8 af[2], bfr[4];
#pragma unroll
    for (int i = 0; i < 2; i++) af[i] = *(const bf16x8*)(As + (wm + i * 16 + fr) * 32 + fk);
#pragma unroll
    for (int j = 0; j < 4; j++) bfr[j] = *(const bf16x8*)(Bs + (wn + j * 16 + fr) * 32 + fk);
#pragma unroll
    for (int i = 0; i < 2; i++)
#pragma unroll
      for (int j = 0; j < 4; j++)
        acc[i][j] = __builtin_amdgcn_mfma_f32_16x16x32_bf16(af[i], bfr[j], acc[i][j], 0, 0, 0);
  }
  int cr = (lane >> 4) * 4, cc = lane & 15;
#pragma unroll
  for (int i = 0; i < 2; i++)
#pragma unroll
    for (int r = 0; r < 4; r++) {
      int q = m0 + wm + i * 16 + cr + r;
      float* zrow = Z + ((long)b * SQL + q) * DIM;
#pragma unroll
      for (int j = 0; j < 4; j++)
        zrow[n0 + wn + j * 16 + cc] = acc[i][j][r];
    }
}

// ---------------- launch ----------------

extern "C" void kernel_launch(void* const* d_in, const int* in_sizes, int n_in,
                              void* d_out, int out_size, void* d_ws, size_t ws_size,
                              hipStream_t stream) {
  const float* Q = (const float*)d_in[0];
  const float* K = (const float*)d_in[1];
  const float* V = (const float*)d_in[2];
  const float* rel = (const float*)d_in[3];
  float* attn = (float*)d_out;                       // [4][2048][2048]
  float* Z = attn + (long)BATCH * SQL * SKL;         // [4][2048][512]

  char* ws = (char*)d_ws;
  u16* Qb   = (u16*)ws;                    //  8 MiB  bf16 Q [b][q][d]
  u16* Kb   = (u16*)(ws + 8388608);        //  8 MiB  bf16 K [b][k][d]
  u16* Vt   = (u16*)(ws + 16777216);       //  8 MiB  bf16 V^T [b][d][k]
  u16* relb = (u16*)(ws + 25165824);       //  288 KiB bf16 rel padded [288][512]
  float* Qrel = (float*)(ws + 25460736);   //  9 MiB  fp32 Qrel [8192][288]
  u16* S    = (u16*)(ws + 34897920);       //  32 MiB bf16 scores/probs [b][q][k]

  cvt_kernel<<<4096, 256, 0, stream>>>((const f32x4*)Q, (u16x4*)Qb, 1048576);
  cvt_kernel<<<4096, 256, 0, stream>>>((const f32x4*)K, (u16x4*)Kb, 1048576);
  cvt_rel_kernel<<<576, 256, 0, stream>>>(rel, relb);
  transpose_v_kernel<<<dim3(64, 16, BATCH), dim3(32, 8), 0, stream>>>(V, Vt);
  qrel_kernel<<<dim3(128, 9), 256, 0, stream>>>(Qb, relb, Qrel);
  energy_kernel<<<dim3(16, 16, BATCH), 256, 0, stream>>>(Qb, Kb, Qrel, S);
  softmax_kernel<<<8192, 256, 0, stream>>>(S, attn);
  z_kernel<<<dim3(4, 32, BATCH), 256, 0, stream>>>(S, Vt, Z);
}